// Round 2
// baseline (54.246 us; speedup 1.0000x reference)
//
#include <hip/hip_runtime.h>
#include <math.h>

#define RES     32
#define GCELLS  (RES * RES * RES)       // 32768
#define NPTS    32768
#define BATCH   64
#define NPLANES 3
#define EPS_PD  1e-6f
#define WREG_F  25.0f

#define NBLOCKS 2048                    // 32 chunks/batch * 64 batches
#define PACKED_BYTES ((size_t)BATCH * GCELLS * 16)   // 33,554,432

typedef float f4 __attribute__((ext_vector_type(4)));

// XCD-chunked swizzle: blocks {x, x+8, x+16, ...} (which round-robin onto XCD x)
// take the contiguous work chunks [x*256, (x+1)*256) = batches [8x, 8x+8).
__device__ __forceinline__ int swizzle_chunk(int bid) {
    return (bid & 7) * (NBLOCKS / 8) + (bid >> 3);
}

// ---------------------------------------------------------------------------
// Pre-pass: pack (aux.xyz, vox) into one float4 per cell. Same swizzle as the
// gather kernel so each XCD packs the batches it will later gather.
// 2048 blocks x 256 threads x 4 cells.
// ---------------------------------------------------------------------------
__global__ __launch_bounds__(256) void pack_kernel(
    const float* __restrict__ aux,     // (B*G, 3)
    const float* __restrict__ vox,     // (B*G)
    f4* __restrict__ packed)           // (B*G)
{
    const int chunk = swizzle_chunk(blockIdx.x);
    const int i = chunk * 256 + threadIdx.x;        // cell-group (4 cells)

    const f4* a4 = (const f4*)aux + (size_t)i * 3;
    const f4 a = __builtin_nontemporal_load(a4 + 0);
    const f4 b = __builtin_nontemporal_load(a4 + 1);
    const f4 c = __builtin_nontemporal_load(a4 + 2);
    const f4 v = __builtin_nontemporal_load((const f4*)vox + i);

    f4* o = packed + (size_t)i * 4;
    o[0] = (f4){a.x, a.y, a.z, v.x};
    o[1] = (f4){a.w, b.x, b.y, v.y};
    o[2] = (f4){b.z, b.w, c.x, v.z};
    o[3] = (f4){c.y, c.z, c.w, v.w};
}

// ---------------------------------------------------------------------------
// Main: 4 points/thread, 3 planes each. Plane constants are block-uniform
// (one batch per block) -> SGPRs, reciprocal hoisted. All 12 gathers issued
// before any consumption (MLP). Single float4 load per cell.
// ---------------------------------------------------------------------------
__global__ __launch_bounds__(256) void sym_packed_kernel(
    const float* __restrict__ pc,      // (B, N, 3)
    const f4* __restrict__ packed,     // (B*G)
    const float* __restrict__ planes,  // (3, B, 4)
    float* __restrict__ part)          // (NBLOCKS)
{
    const int chunk = swizzle_chunk(blockIdx.x);
    const int b  = chunk >> 5;                      // batch (32 chunks/batch)
    const int cb = chunk & 31;                      // chunk within batch

    // block-uniform plane constants
    float nx[3], ny[3], nz[3], dd[3], sc[3];
    #pragma unroll
    for (int pl = 0; pl < NPLANES; ++pl) {
        const float* P = planes + ((pl * BATCH + b) << 2);
        nx[pl] = P[0]; ny[pl] = P[1]; nz[pl] = P[2]; dd[pl] = P[3];
        sc[pl] = 2.0f / (nx[pl]*nx[pl] + ny[pl]*ny[pl] + nz[pl]*nz[pl]);
    }

    // 4 consecutive points: 3 aligned float4, nontemporal (stream, keep L2)
    const int p0 = b * NPTS + cb * 1024 + threadIdx.x * 4;
    const f4* pc4 = (const f4*)pc + (size_t)(p0 >> 2) * 3;
    const f4 A = __builtin_nontemporal_load(pc4 + 0);
    const f4 Bv = __builtin_nontemporal_load(pc4 + 1);
    const f4 C = __builtin_nontemporal_load(pc4 + 2);

    const float px[4] = {A.x, A.w, Bv.z, C.y};
    const float py[4] = {A.y, Bv.x, Bv.w, C.z};
    const float pz[4] = {A.z, Bv.y, C.x, C.w};

    const f4* pb = packed + (size_t)b * GCELLS;

    float t_[12];
    f4 pv[12];
    #pragma unroll
    for (int pt = 0; pt < 4; ++pt) {
        #pragma unroll
        for (int pl = 0; pl < NPLANES; ++pl) {
            const int k = pt * 3 + pl;
            const float tt = (px[pt]*nx[pl] + py[pt]*ny[pl] + pz[pt]*nz[pl]
                              + dd[pl]) * sc[pl];
            t_[k] = tt;
            const float qx = px[pt] - tt * nx[pl];
            const float qy = py[pt] - tt * ny[pl];
            const float qz = pz[pt] - tt * nz[pl];
            int ix = (int)((qx + 0.5f) * (float)RES);
            int iy = (int)((qy + 0.5f) * (float)RES);
            int iz = (int)((qz + 0.5f) * (float)RES);
            ix = min(RES - 1, max(0, ix));
            iy = min(RES - 1, max(0, iy));
            iz = min(RES - 1, max(0, iz));
            pv[k] = pb[(ix << 10) + (iy << 5) + iz];
        }
    }

    float acc = 0.0f;
    #pragma unroll
    for (int pt = 0; pt < 4; ++pt) {
        #pragma unroll
        for (int pl = 0; pl < NPLANES; ++pl) {
            const int k = pt * 3 + pl;
            const float tt = t_[k];
            const float dx = (px[pt] - tt * nx[pl]) - pv[k].x + EPS_PD;
            const float dy = (py[pt] - tt * ny[pl]) - pv[k].y + EPS_PD;
            const float dz = (pz[pt] - tt * nz[pl]) - pv[k].z + EPS_PD;
            acc += sqrtf(dx*dx + dy*dy + dz*dz) * (1.0f - pv[k].w);
        }
    }

    // wave + block reduction
    #pragma unroll
    for (int off = 32; off > 0; off >>= 1)
        acc += __shfl_down(acc, off);

    __shared__ float ws[4];
    if ((threadIdx.x & 63) == 0) ws[threadIdx.x >> 6] = acc;
    __syncthreads();
    if (threadIdx.x == 0)
        part[blockIdx.x] = ws[0] + ws[1] + ws[2] + ws[3];
}

// ---------------------------------------------------------------------------
// Fallback (ws too small for the packed table): same structure, unpacked
// gathers from aux/vox directly.
// ---------------------------------------------------------------------------
__global__ __launch_bounds__(256) void sym_fallback_kernel(
    const float* __restrict__ pc,
    const float* __restrict__ aux,
    const float* __restrict__ vox,
    const float* __restrict__ planes,
    float* __restrict__ part)
{
    const int chunk = swizzle_chunk(blockIdx.x);
    const int b  = chunk >> 5;
    const int cb = chunk & 31;

    float nx[3], ny[3], nz[3], dd[3], sc[3];
    #pragma unroll
    for (int pl = 0; pl < NPLANES; ++pl) {
        const float* P = planes + ((pl * BATCH + b) << 2);
        nx[pl] = P[0]; ny[pl] = P[1]; nz[pl] = P[2]; dd[pl] = P[3];
        sc[pl] = 2.0f / (nx[pl]*nx[pl] + ny[pl]*ny[pl] + nz[pl]*nz[pl]);
    }

    const int p0 = b * NPTS + cb * 1024 + threadIdx.x * 4;
    const f4* pc4 = (const f4*)pc + (size_t)(p0 >> 2) * 3;
    const f4 A = __builtin_nontemporal_load(pc4 + 0);
    const f4 Bv = __builtin_nontemporal_load(pc4 + 1);
    const f4 C = __builtin_nontemporal_load(pc4 + 2);

    const float px[4] = {A.x, A.w, Bv.z, C.y};
    const float py[4] = {A.y, Bv.x, Bv.w, C.z};
    const float pz[4] = {A.z, Bv.y, C.x, C.w};

    float t_[12], vv[12], tx[12], ty[12], tz[12];
    #pragma unroll
    for (int pt = 0; pt < 4; ++pt) {
        #pragma unroll
        for (int pl = 0; pl < NPLANES; ++pl) {
            const int k = pt * 3 + pl;
            const float tt = (px[pt]*nx[pl] + py[pt]*ny[pl] + pz[pt]*nz[pl]
                              + dd[pl]) * sc[pl];
            t_[k] = tt;
            const float qx = px[pt] - tt * nx[pl];
            const float qy = py[pt] - tt * ny[pl];
            const float qz = pz[pt] - tt * nz[pl];
            int ix = (int)((qx + 0.5f) * (float)RES);
            int iy = (int)((qy + 0.5f) * (float)RES);
            int iz = (int)((qz + 0.5f) * (float)RES);
            ix = min(RES - 1, max(0, ix));
            iy = min(RES - 1, max(0, iy));
            iz = min(RES - 1, max(0, iz));
            const int gi = b * GCELLS + (ix << 10) + (iy << 5) + iz;
            vv[k] = vox[gi];
            tx[k] = aux[gi * 3 + 0];
            ty[k] = aux[gi * 3 + 1];
            tz[k] = aux[gi * 3 + 2];
        }
    }

    float acc = 0.0f;
    #pragma unroll
    for (int pt = 0; pt < 4; ++pt) {
        #pragma unroll
        for (int pl = 0; pl < NPLANES; ++pl) {
            const int k = pt * 3 + pl;
            const float tt = t_[k];
            const float dx = (px[pt] - tt * nx[pl]) - tx[k] + EPS_PD;
            const float dy = (py[pt] - tt * ny[pl]) - ty[k] + EPS_PD;
            const float dz = (pz[pt] - tt * nz[pl]) - tz[k] + EPS_PD;
            acc += sqrtf(dx*dx + dy*dy + dz*dz) * (1.0f - vv[k]);
        }
    }

    #pragma unroll
    for (int off = 32; off > 0; off >>= 1)
        acc += __shfl_down(acc, off);

    __shared__ float ws[4];
    if ((threadIdx.x & 63) == 0) ws[threadIdx.x >> 6] = acc;
    __syncthreads();
    if (threadIdx.x == 0)
        part[blockIdx.x] = ws[0] + ws[1] + ws[2] + ws[3];
}

// ---------------------------------------------------------------------------
// Finalize: sum partials + plane-normal regularizer -> out[0].
// ---------------------------------------------------------------------------
__global__ __launch_bounds__(256) void finalize_kernel(
    const float* __restrict__ part, int n_part,
    const float* __restrict__ planes,
    float* __restrict__ out)
{
    __shared__ float sdata[256];

    float s = 0.0f;
    for (int i = threadIdx.x; i < n_part; i += 256)
        s += part[i];

    float r = 0.0f;
    if (threadIdx.x < BATCH) {
        const int b = threadIdx.x;
        float nv[3][3];
        #pragma unroll
        for (int p = 0; p < NPLANES; ++p) {
            const float nxv = planes[((p * BATCH + b) << 2) + 0];
            const float nyv = planes[((p * BATCH + b) << 2) + 1];
            const float nzv = planes[((p * BATCH + b) << 2) + 2];
            float nrm = sqrtf(nxv*nxv + nyv*nyv + nzv*nzv);
            nrm = fmaxf(nrm, 1e-12f);
            nv[p][0] = nxv / nrm;
            nv[p][1] = nyv / nrm;
            nv[p][2] = nzv / nrm;
        }
        #pragma unroll
        for (int i2 = 0; i2 < 3; ++i2) {
            #pragma unroll
            for (int j = 0; j < 3; ++j) {
                const float m = nv[i2][j] * nv[j][i2] - (i2 == j ? 1.0f : 0.0f);
                r += m * m;
            }
        }
    }

    float val = s * (1.0f / (float)BATCH) + r * (WREG_F / (float)BATCH);

    sdata[threadIdx.x] = val;
    __syncthreads();
    #pragma unroll
    for (int off = 128; off > 0; off >>= 1) {
        if (threadIdx.x < off) sdata[threadIdx.x] += sdata[threadIdx.x + off];
        __syncthreads();
    }

    if (threadIdx.x == 0) out[0] = sdata[0];
}

// ---------------------------------------------------------------------------
extern "C" void kernel_launch(void* const* d_in, const int* in_sizes, int n_in,
                              void* d_out, int out_size, void* d_ws, size_t ws_size,
                              hipStream_t stream)
{
    const float* pc     = (const float*)d_in[0];
    const float* aux    = (const float*)d_in[1];
    const float* vox    = (const float*)d_in[2];
    const float* planes = (const float*)d_in[3];
    float* out = (float*)d_out;

    if (ws_size >= PACKED_BYTES + NBLOCKS * sizeof(float)) {
        f4*    packed = (f4*)d_ws;
        float* part   = (float*)((char*)d_ws + PACKED_BYTES);
        pack_kernel<<<NBLOCKS, 256, 0, stream>>>(aux, vox, packed);
        sym_packed_kernel<<<NBLOCKS, 256, 0, stream>>>(pc, packed, planes, part);
        finalize_kernel<<<1, 256, 0, stream>>>(part, NBLOCKS, planes, out);
    } else {
        float* part = (float*)d_ws;
        sym_fallback_kernel<<<NBLOCKS, 256, 0, stream>>>(pc, aux, vox, planes, part);
        finalize_kernel<<<1, 256, 0, stream>>>(part, NBLOCKS, planes, out);
    }
}

// Round 3
// 41.187 us; speedup vs baseline: 1.3170x; 1.3170x over previous
//
#include <hip/hip_runtime.h>
#include <math.h>

#define RES     32
#define GCELLS  (RES * RES * RES)       // 32768
#define NPTS    32768
#define BATCH   64
#define NPLANES 3
#define EPS_PD  1e-6f
#define WREG_F  25.0f

#define NBLOCKS 2048                    // 32 chunks/batch * 64 batches
#define PACKED_BYTES ((size_t)BATCH * GCELLS * 8)    // 16,777,216 (fp16 x4)

typedef float    f4 __attribute__((ext_vector_type(4)));
typedef _Float16 h4 __attribute__((ext_vector_type(4)));   // 8 B
typedef _Float16 h8 __attribute__((ext_vector_type(8)));   // 16 B

// XCD-chunked swizzle: blocks {x, x+8, x+16, ...} (round-robin onto XCD x)
// take contiguous work chunks [x*256, (x+1)*256) = batches [8x, 8x+8).
__device__ __forceinline__ int swizzle_chunk(int bid) {
    return (bid & 7) * (NBLOCKS / 8) + (bid >> 3);
}

// ---------------------------------------------------------------------------
// Pre-pass: pack (aux.xyz, vox) -> one h4 (8 B) per cell. Same swizzle as the
// gather kernel so each XCD packs (and keeps in its L2) the batches it will
// later gather. 2048 blocks x 256 threads x 4 cells.
// ---------------------------------------------------------------------------
__global__ __launch_bounds__(256) void pack_kernel(
    const float* __restrict__ aux,     // (B*G, 3)
    const float* __restrict__ vox,     // (B*G)
    h8* __restrict__ packed)           // (B*G/2) -- two cells per h8
{
    const int chunk = swizzle_chunk(blockIdx.x);
    const int i = chunk * 256 + threadIdx.x;        // cell-group (4 cells)

    const f4* a4 = (const f4*)aux + (size_t)i * 3;
    const f4 a = __builtin_nontemporal_load(a4 + 0);
    const f4 b = __builtin_nontemporal_load(a4 + 1);
    const f4 c = __builtin_nontemporal_load(a4 + 2);
    const f4 v = __builtin_nontemporal_load((const f4*)vox + i);

    // cells: 0:(a.x,a.y,a.z,v.x) 1:(a.w,b.x,b.y,v.y) 2:(b.z,b.w,c.x,v.z) 3:(c.y,c.z,c.w,v.w)
    h8 o01 = { (_Float16)a.x, (_Float16)a.y, (_Float16)a.z, (_Float16)v.x,
               (_Float16)a.w, (_Float16)b.x, (_Float16)b.y, (_Float16)v.y };
    h8 o23 = { (_Float16)b.z, (_Float16)b.w, (_Float16)c.x, (_Float16)v.z,
               (_Float16)c.y, (_Float16)c.z, (_Float16)c.w, (_Float16)v.w };

    h8* o = packed + (size_t)i * 2;
    o[0] = o01;       // normal stores: keep the packed table hot in this L2
    o[1] = o23;
}

// ---------------------------------------------------------------------------
// Main: 4 points/thread, 3 planes each. One batch per block -> plane
// constants uniform (SGPRs). All 12 gathers are single 8-B loads from the
// L2-resident fp16 table.
// ---------------------------------------------------------------------------
__global__ __launch_bounds__(256) void sym_packed_kernel(
    const float* __restrict__ pc,      // (B, N, 3)
    const h4* __restrict__ packed,     // (B*G)
    const float* __restrict__ planes,  // (3, B, 4)
    float* __restrict__ part)          // (NBLOCKS)
{
    const int chunk = swizzle_chunk(blockIdx.x);
    const int b  = chunk >> 5;                      // batch (32 chunks/batch)
    const int cb = chunk & 31;                      // chunk within batch

    float nx[3], ny[3], nz[3], dd[3], sc[3];
    #pragma unroll
    for (int pl = 0; pl < NPLANES; ++pl) {
        const float* P = planes + ((pl * BATCH + b) << 2);
        nx[pl] = P[0]; ny[pl] = P[1]; nz[pl] = P[2]; dd[pl] = P[3];
        sc[pl] = 2.0f / (nx[pl]*nx[pl] + ny[pl]*ny[pl] + nz[pl]*nz[pl]);
    }

    // 4 consecutive points: 3 aligned float4, nontemporal (stream past L2)
    const int p0 = b * NPTS + cb * 1024 + threadIdx.x * 4;
    const f4* pc4 = (const f4*)pc + (size_t)(p0 >> 2) * 3;
    const f4 A  = __builtin_nontemporal_load(pc4 + 0);
    const f4 Bv = __builtin_nontemporal_load(pc4 + 1);
    const f4 C  = __builtin_nontemporal_load(pc4 + 2);

    const float px[4] = {A.x, A.w, Bv.z, C.y};
    const float py[4] = {A.y, Bv.x, Bv.w, C.z};
    const float pz[4] = {A.z, Bv.y, C.x, C.w};

    const h4* pb = packed + (size_t)b * GCELLS;

    float t_[12];
    h4 pv[12];
    #pragma unroll
    for (int pt = 0; pt < 4; ++pt) {
        #pragma unroll
        for (int pl = 0; pl < NPLANES; ++pl) {
            const int k = pt * 3 + pl;
            const float tt = (px[pt]*nx[pl] + py[pt]*ny[pl] + pz[pt]*nz[pl]
                              + dd[pl]) * sc[pl];
            t_[k] = tt;
            const float qx = px[pt] - tt * nx[pl];
            const float qy = py[pt] - tt * ny[pl];
            const float qz = pz[pt] - tt * nz[pl];
            int ix = (int)((qx + 0.5f) * (float)RES);
            int iy = (int)((qy + 0.5f) * (float)RES);
            int iz = (int)((qz + 0.5f) * (float)RES);
            ix = min(RES - 1, max(0, ix));
            iy = min(RES - 1, max(0, iy));
            iz = min(RES - 1, max(0, iz));
            pv[k] = pb[(ix << 10) + (iy << 5) + iz];
        }
    }

    float acc = 0.0f;
    #pragma unroll
    for (int pt = 0; pt < 4; ++pt) {
        #pragma unroll
        for (int pl = 0; pl < NPLANES; ++pl) {
            const int k = pt * 3 + pl;
            const float tt = t_[k];
            const float dx = (px[pt] - tt * nx[pl]) - (float)pv[k].x + EPS_PD;
            const float dy = (py[pt] - tt * ny[pl]) - (float)pv[k].y + EPS_PD;
            const float dz = (pz[pt] - tt * nz[pl]) - (float)pv[k].z + EPS_PD;
            acc += sqrtf(dx*dx + dy*dy + dz*dz) * (1.0f - (float)pv[k].w);
        }
    }

    #pragma unroll
    for (int off = 32; off > 0; off >>= 1)
        acc += __shfl_down(acc, off);

    __shared__ float ws[4];
    if ((threadIdx.x & 63) == 0) ws[threadIdx.x >> 6] = acc;
    __syncthreads();
    if (threadIdx.x == 0)
        part[blockIdx.x] = ws[0] + ws[1] + ws[2] + ws[3];
}

// ---------------------------------------------------------------------------
// Fallback (ws too small): direct fp32 gathers.
// ---------------------------------------------------------------------------
__global__ __launch_bounds__(256) void sym_fallback_kernel(
    const float* __restrict__ pc,
    const float* __restrict__ aux,
    const float* __restrict__ vox,
    const float* __restrict__ planes,
    float* __restrict__ part)
{
    const int chunk = swizzle_chunk(blockIdx.x);
    const int b  = chunk >> 5;
    const int cb = chunk & 31;

    float nx[3], ny[3], nz[3], dd[3], sc[3];
    #pragma unroll
    for (int pl = 0; pl < NPLANES; ++pl) {
        const float* P = planes + ((pl * BATCH + b) << 2);
        nx[pl] = P[0]; ny[pl] = P[1]; nz[pl] = P[2]; dd[pl] = P[3];
        sc[pl] = 2.0f / (nx[pl]*nx[pl] + ny[pl]*ny[pl] + nz[pl]*nz[pl]);
    }

    const int p0 = b * NPTS + cb * 1024 + threadIdx.x * 4;
    const f4* pc4 = (const f4*)pc + (size_t)(p0 >> 2) * 3;
    const f4 A  = __builtin_nontemporal_load(pc4 + 0);
    const f4 Bv = __builtin_nontemporal_load(pc4 + 1);
    const f4 C  = __builtin_nontemporal_load(pc4 + 2);

    const float px[4] = {A.x, A.w, Bv.z, C.y};
    const float py[4] = {A.y, Bv.x, Bv.w, C.z};
    const float pz[4] = {A.z, Bv.y, C.x, C.w};

    float t_[12], vv[12], tx[12], ty[12], tz[12];
    #pragma unroll
    for (int pt = 0; pt < 4; ++pt) {
        #pragma unroll
        for (int pl = 0; pl < NPLANES; ++pl) {
            const int k = pt * 3 + pl;
            const float tt = (px[pt]*nx[pl] + py[pt]*ny[pl] + pz[pt]*nz[pl]
                              + dd[pl]) * sc[pl];
            t_[k] = tt;
            const float qx = px[pt] - tt * nx[pl];
            const float qy = py[pt] - tt * ny[pl];
            const float qz = pz[pt] - tt * nz[pl];
            int ix = (int)((qx + 0.5f) * (float)RES);
            int iy = (int)((qy + 0.5f) * (float)RES);
            int iz = (int)((qz + 0.5f) * (float)RES);
            ix = min(RES - 1, max(0, ix));
            iy = min(RES - 1, max(0, iy));
            iz = min(RES - 1, max(0, iz));
            const int gi = b * GCELLS + (ix << 10) + (iy << 5) + iz;
            vv[k] = vox[gi];
            tx[k] = aux[gi * 3 + 0];
            ty[k] = aux[gi * 3 + 1];
            tz[k] = aux[gi * 3 + 2];
        }
    }

    float acc = 0.0f;
    #pragma unroll
    for (int pt = 0; pt < 4; ++pt) {
        #pragma unroll
        for (int pl = 0; pl < NPLANES; ++pl) {
            const int k = pt * 3 + pl;
            const float tt = t_[k];
            const float dx = (px[pt] - tt * nx[pl]) - tx[k] + EPS_PD;
            const float dy = (py[pt] - tt * ny[pl]) - ty[k] + EPS_PD;
            const float dz = (pz[pt] - tt * nz[pl]) - tz[k] + EPS_PD;
            acc += sqrtf(dx*dx + dy*dy + dz*dz) * (1.0f - vv[k]);
        }
    }

    #pragma unroll
    for (int off = 32; off > 0; off >>= 1)
        acc += __shfl_down(acc, off);

    __shared__ float ws[4];
    if ((threadIdx.x & 63) == 0) ws[threadIdx.x >> 6] = acc;
    __syncthreads();
    if (threadIdx.x == 0)
        part[blockIdx.x] = ws[0] + ws[1] + ws[2] + ws[3];
}

// ---------------------------------------------------------------------------
// Finalize: sum partials + plane-normal regularizer -> out[0].
// ---------------------------------------------------------------------------
__global__ __launch_bounds__(256) void finalize_kernel(
    const float* __restrict__ part, int n_part,
    const float* __restrict__ planes,
    float* __restrict__ out)
{
    __shared__ float sdata[256];

    float s = 0.0f;
    for (int i = threadIdx.x; i < n_part; i += 256)
        s += part[i];

    float r = 0.0f;
    if (threadIdx.x < BATCH) {
        const int b = threadIdx.x;
        float nv[3][3];
        #pragma unroll
        for (int p = 0; p < NPLANES; ++p) {
            const float nxv = planes[((p * BATCH + b) << 2) + 0];
            const float nyv = planes[((p * BATCH + b) << 2) + 1];
            const float nzv = planes[((p * BATCH + b) << 2) + 2];
            float nrm = sqrtf(nxv*nxv + nyv*nyv + nzv*nzv);
            nrm = fmaxf(nrm, 1e-12f);
            nv[p][0] = nxv / nrm;
            nv[p][1] = nyv / nrm;
            nv[p][2] = nzv / nrm;
        }
        #pragma unroll
        for (int i2 = 0; i2 < 3; ++i2) {
            #pragma unroll
            for (int j = 0; j < 3; ++j) {
                const float m = nv[i2][j] * nv[j][i2] - (i2 == j ? 1.0f : 0.0f);
                r += m * m;
            }
        }
    }

    float val = s * (1.0f / (float)BATCH) + r * (WREG_F / (float)BATCH);

    sdata[threadIdx.x] = val;
    __syncthreads();
    #pragma unroll
    for (int off = 128; off > 0; off >>= 1) {
        if (threadIdx.x < off) sdata[threadIdx.x] += sdata[threadIdx.x + off];
        __syncthreads();
    }

    if (threadIdx.x == 0) out[0] = sdata[0];
}

// ---------------------------------------------------------------------------
extern "C" void kernel_launch(void* const* d_in, const int* in_sizes, int n_in,
                              void* d_out, int out_size, void* d_ws, size_t ws_size,
                              hipStream_t stream)
{
    const float* pc     = (const float*)d_in[0];
    const float* aux    = (const float*)d_in[1];
    const float* vox    = (const float*)d_in[2];
    const float* planes = (const float*)d_in[3];
    float* out = (float*)d_out;

    if (ws_size >= PACKED_BYTES + NBLOCKS * sizeof(float)) {
        h8*    packed = (h8*)d_ws;
        float* part   = (float*)((char*)d_ws + PACKED_BYTES);
        pack_kernel<<<NBLOCKS, 256, 0, stream>>>(aux, vox, packed);
        sym_packed_kernel<<<NBLOCKS, 256, 0, stream>>>(pc, (const h4*)d_ws, planes, part);
        finalize_kernel<<<1, 256, 0, stream>>>(part, NBLOCKS, planes, out);
    } else {
        float* part = (float*)d_ws;
        sym_fallback_kernel<<<NBLOCKS, 256, 0, stream>>>(pc, aux, vox, planes, part);
        finalize_kernel<<<1, 256, 0, stream>>>(part, NBLOCKS, planes, out);
    }
}

// Round 4
// 31.130 us; speedup vs baseline: 1.7426x; 1.3231x over previous
//
#include <hip/hip_runtime.h>
#include <math.h>

#define RES     32
#define GCELLS  (RES * RES * RES)       // 32768
#define NPTS    32768
#define BATCH   64
#define NPLANES 3
#define EPS_PD  1e-6f
#define WREG_F  25.0f

#define PACK_BLOCKS 2048
#define SYM_BLOCKS  256                 // 1 per CU, 4 per batch
#define SYM_THREADS 1024
#define NWAVES      (SYM_THREADS / 64)
#define PACKED_BYTES ((size_t)BATCH * GCELLS * 4)    // 8 MiB (u8 x4 per cell)

typedef float        f4 __attribute__((ext_vector_type(4)));
typedef unsigned int u32;
typedef u32          u4 __attribute__((ext_vector_type(4)));

// XCD-chunked swizzle for the 2048-block pack grid: XCD x gets chunks
// [x*256, (x+1)*256) = cells of batches [8x, 8x+8).
__device__ __forceinline__ int swizzle_chunk(int bid) {
    return (bid & 7) * (PACK_BLOCKS / 8) + (bid >> 3);
}

// ---------------------------------------------------------------------------
// Pre-pass: quantize (aux.xyz, vox) -> u8x4 (4 B/cell). XCD-swizzled so each
// XCD's L2 ends up holding the 8 batch tables (8 x 128 KB = 1 MB) that its
// sym blocks will stage.
// ---------------------------------------------------------------------------
__global__ __launch_bounds__(256) void pack_u8_kernel(
    const float* __restrict__ aux,     // (B*G, 3)
    const float* __restrict__ vox,     // (B*G)
    u32* __restrict__ packed)          // (B*G)
{
    const int chunk = swizzle_chunk(blockIdx.x);
    const int i = chunk * 256 + threadIdx.x;        // group of 4 cells

    const f4* a4 = (const f4*)aux + (size_t)i * 3;
    const f4 a = __builtin_nontemporal_load(a4 + 0);
    const f4 b = __builtin_nontemporal_load(a4 + 1);
    const f4 c = __builtin_nontemporal_load(a4 + 2);
    const f4 v = __builtin_nontemporal_load((const f4*)vox + i);

    const float cx[4] = {a.x, a.w, b.z, c.y};
    const float cy[4] = {a.y, b.x, b.w, c.z};
    const float cz[4] = {a.z, b.y, c.x, c.w};
    const float cv[4] = {v.x, v.y, v.z, v.w};

    u4 o;
    #pragma unroll
    for (int j = 0; j < 4; ++j) {
        // u = round_half_up((x+0.5)*255) ; x*255 + 127.5 + 0.5 = x*255 + 128
        const u32 ux = (u32)fmaf(cx[j], 255.0f, 128.0f);
        const u32 uy = (u32)fmaf(cy[j], 255.0f, 128.0f);
        const u32 uz = (u32)fmaf(cz[j], 255.0f, 128.0f);
        const u32 uv = (u32)fmaf(cv[j], 255.0f, 0.5f);
        o[j] = ux | (uy << 8) | (uz << 16) | (uv << 24);
    }
    *((u4*)packed + i) = o;            // normal store: keep table hot in L2
}

// ---------------------------------------------------------------------------
// Main: 1 block/CU, whole batch table (128 KB u8x4) staged in LDS.
// 8 points/thread x 3 planes; gathers are ds_read_b32 from LDS.
// ---------------------------------------------------------------------------
__global__ __launch_bounds__(SYM_THREADS, 4) void sym_lds_kernel(
    const float* __restrict__ pc,      // (B, N, 3)
    const u32* __restrict__ packed,    // (B*G) u8x4
    const float* __restrict__ planes,  // (3, B, 4)
    float* __restrict__ part)          // (SYM_BLOCKS)
{
    __shared__ u32  tab[GCELLS];       // 128 KiB
    __shared__ float wsum[NWAVES];

    const int t    = threadIdx.x;
    const int blk  = blockIdx.x;
    const int xcd  = blk & 7;
    const int slot = blk >> 3;                 // 0..31 on this XCD
    const int b    = xcd * 8 + (slot >> 2);    // batch
    const int c    = slot & 3;                 // quarter of the batch

    // ---- stage the batch table: 8 x 16 B per thread, linear ----
    const u4* gt = (const u4*)(packed + (size_t)b * GCELLS);
    #pragma unroll
    for (int i = 0; i < 8; ++i) {
        const int k = i * SYM_THREADS + t;
        *(u4*)&tab[k * 4] = gt[k];
    }

    // ---- block-uniform plane constants (scalar loads) ----
    float nx[3], ny[3], nz[3], dd[3], sc[3];
    #pragma unroll
    for (int pl = 0; pl < NPLANES; ++pl) {
        const float* P = planes + ((pl * BATCH + b) << 2);
        nx[pl] = P[0]; ny[pl] = P[1]; nz[pl] = P[2]; dd[pl] = P[3];
        sc[pl] = 2.0f / (nx[pl]*nx[pl] + ny[pl]*ny[pl] + nz[pl]*nz[pl]);
    }

    __syncthreads();

    // ---- 8 consecutive points: 6 aligned float4 (96 B), nontemporal ----
    const f4* pc4 = (const f4*)pc
                  + (((size_t)(b * NPTS + c * 8192) * 3) >> 2)
                  + (size_t)t * 6;
    f4 A[6];
    #pragma unroll
    for (int i = 0; i < 6; ++i) A[i] = __builtin_nontemporal_load(pc4 + i);
    const float* f = (const float*)A;

    const float SHIFT  = 0.5f + EPS_PD;        // fold +0.5 and +eps into q
    const float IOFF   = -32.0f * EPS_PD;      // undo eps in the index path
    const float INV255 = 1.0f / 255.0f;

    float acc = 0.0f;
    #pragma unroll
    for (int p = 0; p < 8; ++p) {
        const float px = f[3*p], py = f[3*p+1], pz = f[3*p+2];
        const float pxs = px + SHIFT, pys = py + SHIFT, pzs = pz + SHIFT;
        #pragma unroll
        for (int pl = 0; pl < NPLANES; ++pl) {
            const float tt  = (px*nx[pl] + py*ny[pl] + pz*nz[pl] + dd[pl]) * sc[pl];
            const float qxs = fmaf(-tt, nx[pl], pxs);   // qx + 0.5 + eps
            const float qys = fmaf(-tt, ny[pl], pys);
            const float qzs = fmaf(-tt, nz[pl], pzs);
            // (qx+0.5)*32 = qxs*32 - 32*eps ; med3 clamp ; trunc
            const float xf = truncf(fminf(fmaxf(fmaf(qxs, 32.0f, IOFF), 0.0f), 31.0f));
            const float yf = truncf(fminf(fmaxf(fmaf(qys, 32.0f, IOFF), 0.0f), 31.0f));
            const float zf = truncf(fminf(fmaxf(fmaf(qzs, 32.0f, IOFF), 0.0f), 31.0f));
            const u32 g    = (u32)fmaf(fmaf(xf, 32.0f, yf), 32.0f, zf);
            const u32 cell = tab[g];
            // dx = qx - (u/255 - 0.5) + eps = qxs - u*INV255
            const float dx = fmaf((float)(cell & 255u),         -INV255, qxs);
            const float dy = fmaf((float)((cell >> 8) & 255u),  -INV255, qys);
            const float dz = fmaf((float)((cell >> 16) & 255u), -INV255, qzs);
            const float w  = fmaf((float)(cell >> 24),          -INV255, 1.0f);
            acc = fmaf(sqrtf(dx*dx + dy*dy + dz*dz), w, acc);
        }
    }

    // ---- reduce ----
    #pragma unroll
    for (int off = 32; off > 0; off >>= 1)
        acc += __shfl_down(acc, off);
    if ((t & 63) == 0) wsum[t >> 6] = acc;
    __syncthreads();
    if (t == 0) {
        float s = 0.0f;
        #pragma unroll
        for (int w2 = 0; w2 < NWAVES; ++w2) s += wsum[w2];
        part[blk] = s;
    }
}

// ---------------------------------------------------------------------------
// Fallback (ws too small): direct fp32 gathers, 2048 blocks.
// ---------------------------------------------------------------------------
__global__ __launch_bounds__(256) void sym_fallback_kernel(
    const float* __restrict__ pc,
    const float* __restrict__ aux,
    const float* __restrict__ vox,
    const float* __restrict__ planes,
    float* __restrict__ part)
{
    const int chunk = swizzle_chunk(blockIdx.x);
    const int b  = chunk >> 5;
    const int cb = chunk & 31;

    float nx[3], ny[3], nz[3], dd[3], sc[3];
    #pragma unroll
    for (int pl = 0; pl < NPLANES; ++pl) {
        const float* P = planes + ((pl * BATCH + b) << 2);
        nx[pl] = P[0]; ny[pl] = P[1]; nz[pl] = P[2]; dd[pl] = P[3];
        sc[pl] = 2.0f / (nx[pl]*nx[pl] + ny[pl]*ny[pl] + nz[pl]*nz[pl]);
    }

    const int p0 = b * NPTS + cb * 1024 + threadIdx.x * 4;
    const f4* pc4 = (const f4*)pc + (size_t)(p0 >> 2) * 3;
    const f4 A  = __builtin_nontemporal_load(pc4 + 0);
    const f4 Bv = __builtin_nontemporal_load(pc4 + 1);
    const f4 C  = __builtin_nontemporal_load(pc4 + 2);

    const float px[4] = {A.x, A.w, Bv.z, C.y};
    const float py[4] = {A.y, Bv.x, Bv.w, C.z};
    const float pz[4] = {A.z, Bv.y, C.x, C.w};

    float acc = 0.0f;
    #pragma unroll
    for (int pt = 0; pt < 4; ++pt) {
        #pragma unroll
        for (int pl = 0; pl < NPLANES; ++pl) {
            const float tt = (px[pt]*nx[pl] + py[pt]*ny[pl] + pz[pt]*nz[pl]
                              + dd[pl]) * sc[pl];
            const float qx = px[pt] - tt * nx[pl];
            const float qy = py[pt] - tt * ny[pl];
            const float qz = pz[pt] - tt * nz[pl];
            int ix = (int)((qx + 0.5f) * (float)RES);
            int iy = (int)((qy + 0.5f) * (float)RES);
            int iz = (int)((qz + 0.5f) * (float)RES);
            ix = min(RES - 1, max(0, ix));
            iy = min(RES - 1, max(0, iy));
            iz = min(RES - 1, max(0, iz));
            const int gi = b * GCELLS + (ix << 10) + (iy << 5) + iz;
            const float v  = vox[gi];
            const float dx = qx - aux[gi*3+0] + EPS_PD;
            const float dy = qy - aux[gi*3+1] + EPS_PD;
            const float dz = qz - aux[gi*3+2] + EPS_PD;
            acc += sqrtf(dx*dx + dy*dy + dz*dz) * (1.0f - v);
        }
    }

    #pragma unroll
    for (int off = 32; off > 0; off >>= 1)
        acc += __shfl_down(acc, off);

    __shared__ float ws[4];
    if ((threadIdx.x & 63) == 0) ws[threadIdx.x >> 6] = acc;
    __syncthreads();
    if (threadIdx.x == 0)
        part[blockIdx.x] = ws[0] + ws[1] + ws[2] + ws[3];
}

// ---------------------------------------------------------------------------
// Finalize: sum partials + plane-normal regularizer -> out[0].
// ---------------------------------------------------------------------------
__global__ __launch_bounds__(256) void finalize_kernel(
    const float* __restrict__ part, int n_part,
    const float* __restrict__ planes,
    float* __restrict__ out)
{
    __shared__ float sdata[256];

    float s = 0.0f;
    for (int i = threadIdx.x; i < n_part; i += 256)
        s += part[i];

    float r = 0.0f;
    if (threadIdx.x < BATCH) {
        const int b = threadIdx.x;
        float nv[3][3];
        #pragma unroll
        for (int p = 0; p < NPLANES; ++p) {
            const float nxv = planes[((p * BATCH + b) << 2) + 0];
            const float nyv = planes[((p * BATCH + b) << 2) + 1];
            const float nzv = planes[((p * BATCH + b) << 2) + 2];
            float nrm = sqrtf(nxv*nxv + nyv*nyv + nzv*nzv);
            nrm = fmaxf(nrm, 1e-12f);
            nv[p][0] = nxv / nrm;
            nv[p][1] = nyv / nrm;
            nv[p][2] = nzv / nrm;
        }
        #pragma unroll
        for (int i2 = 0; i2 < 3; ++i2) {
            #pragma unroll
            for (int j = 0; j < 3; ++j) {
                const float m = nv[i2][j] * nv[j][i2] - (i2 == j ? 1.0f : 0.0f);
                r += m * m;
            }
        }
    }

    float val = s * (1.0f / (float)BATCH) + r * (WREG_F / (float)BATCH);

    sdata[threadIdx.x] = val;
    __syncthreads();
    #pragma unroll
    for (int off = 128; off > 0; off >>= 1) {
        if (threadIdx.x < off) sdata[threadIdx.x] += sdata[threadIdx.x + off];
        __syncthreads();
    }

    if (threadIdx.x == 0) out[0] = sdata[0];
}

// ---------------------------------------------------------------------------
extern "C" void kernel_launch(void* const* d_in, const int* in_sizes, int n_in,
                              void* d_out, int out_size, void* d_ws, size_t ws_size,
                              hipStream_t stream)
{
    const float* pc     = (const float*)d_in[0];
    const float* aux    = (const float*)d_in[1];
    const float* vox    = (const float*)d_in[2];
    const float* planes = (const float*)d_in[3];
    float* out = (float*)d_out;

    if (ws_size >= PACKED_BYTES + SYM_BLOCKS * sizeof(float)) {
        u32*   packed = (u32*)d_ws;
        float* part   = (float*)((char*)d_ws + PACKED_BYTES);
        pack_u8_kernel<<<PACK_BLOCKS, 256, 0, stream>>>(aux, vox, packed);
        sym_lds_kernel<<<SYM_BLOCKS, SYM_THREADS, 0, stream>>>(pc, packed, planes, part);
        finalize_kernel<<<1, 256, 0, stream>>>(part, SYM_BLOCKS, planes, out);
    } else {
        float* part = (float*)d_ws;
        sym_fallback_kernel<<<PACK_BLOCKS, 256, 0, stream>>>(pc, aux, vox, planes, part);
        finalize_kernel<<<1, 256, 0, stream>>>(part, PACK_BLOCKS, planes, out);
    }
}